// Round 5
// baseline (1599.225 us; speedup 1.0000x reference)
//
#include <hip/hip_runtime.h>

#define R_ 3
#define T_ 3
#define N_ 50000
#define OPS_ 24
#define E_ 400000
#define B_ 32
#define MAXDEG_ 8
#define QD_ 128
#define ED_ 128
#define H_ 128
#define G4_ (4*H_)   /* 512 */
#define KW_ 160      /* extended K: 128 h + 25 one-hot + 7 pad */
#define HPAD 168     /* padded LDS row (bf16 elems), 16B-aligned (336 B) */

typedef unsigned short u16;
typedef __attribute__((ext_vector_type(8))) short bf16x8;   // 8 bf16 = 4 VGPRs
typedef __attribute__((ext_vector_type(4))) float f32x4;

#define BF16_ONE ((short)0x3F80)

__device__ __forceinline__ short f2bf(float f){
  union { float f; unsigned u; } v; v.f = f;
  unsigned r = v.u + 0x7fffu + ((v.u >> 16) & 1u);
  return (short)(r >> 16);
}
__device__ __forceinline__ float bf2f(u16 u){
  union { unsigned u; float f; } v; v.u = ((unsigned)u) << 16; return v.f;
}
__device__ __forceinline__ float frcp(float x){ return __builtin_amdgcn_rcpf(x); }
__device__ __forceinline__ float fsig(float x){ return frcp(1.0f + __expf(-x)); }
// tanh(x) = 2*sigmoid(2x) - 1
__device__ __forceinline__ float ftanh(float x){
  return __builtin_fmaf(2.0f, fsig(2.0f * x), -1.0f);
}

// ---------------- query BiLSTM + attention: one block per (r,b) ----------------
__global__ void qattn_kernel(const int* __restrict__ queries, const float* __restrict__ qemb,
    const float* __restrict__ qWih, const float* __restrict__ qWhh,
    const float* __restrict__ qbih, const float* __restrict__ qbhh,
    const float* __restrict__ qlinW, const float* __restrict__ qlinb,
    float* __restrict__ query_attn /* R,T,B,25 */)
{
  int r = blockIdx.x / B_;
  int b = blockIdx.x % B_;
  int tid = threadIdx.x;   // 256
  __shared__ float x[QD_];
  __shared__ float gx[G4_];
  __shared__ float h[H_], c[H_];
  __shared__ float gtmp[G4_];
  __shared__ float hh[2][T_][H_];
  __shared__ float lg[OPS_ + 1];

  int q = queries[b];
  if (tid < QD_) x[tid] = qemb[q * QD_ + tid];
  __syncthreads();

  for (int dir = 0; dir < 2; ++dir){
    const float* Wih = qWih + (size_t)(r * 2 + dir) * G4_ * QD_;
    const float* Whh = qWhh + (size_t)(r * 2 + dir) * G4_ * H_;
    const float* bih = qbih + (r * 2 + dir) * G4_;
    const float* bhh = qbhh + (r * 2 + dir) * G4_;
    for (int j = tid; j < G4_; j += 256){
      const float4* wr = (const float4*)(Wih + (size_t)j * QD_);
      float s = bih[j] + bhh[j];
      for (int k = 0; k < QD_ / 4; ++k){
        float4 wv = wr[k];
        s += wv.x * x[4*k] + wv.y * x[4*k+1] + wv.z * x[4*k+2] + wv.w * x[4*k+3];
      }
      gx[j] = s;
    }
    if (tid < H_){ h[tid] = 0.f; c[tid] = 0.f; }
    __syncthreads();
    for (int t = 0; t < T_; ++t){
      for (int j = tid; j < G4_; j += 256){
        const float4* wr = (const float4*)(Whh + (size_t)j * H_);
        float s = 0.f;
        for (int k = 0; k < H_ / 4; ++k){
          float4 wv = wr[k];
          s += wv.x * h[4*k] + wv.y * h[4*k+1] + wv.z * h[4*k+2] + wv.w * h[4*k+3];
        }
        gtmp[j] = gx[j] + s;
      }
      __syncthreads();
      if (tid < H_){
        float gi = gtmp[tid], gf = gtmp[tid + H_], gg = gtmp[tid + 2*H_], go = gtmp[tid + 3*H_];
        float cn = fsig(gf) * c[tid] + fsig(gi) * ftanh(gg);
        float hn = fsig(go) * ftanh(cn);
        c[tid] = cn; h[tid] = hn;
        hh[dir][t][tid] = hn;
      }
      __syncthreads();
    }
  }

  for (int t = 0; t < T_; ++t){
    if (tid < OPS_ + 1){
      const float* wr = qlinW + tid * (2 * H_);
      float s = qlinb[tid];
      for (int k = 0; k < H_; ++k) s += wr[k] * hh[0][t][k];
      for (int k = 0; k < H_; ++k) s += wr[H_ + k] * hh[1][T_ - 1 - t][k];
      lg[tid] = s;
    }
    __syncthreads();
    if (tid == 0){
      float m = -1e30f;
      for (int o = 0; o < OPS_ + 1; ++o) m = fmaxf(m, lg[o]);
      float sum = 0.f;
      for (int o = 0; o < OPS_ + 1; ++o){ float e = __expf(lg[o] - m); lg[o] = e; sum += e; }
      float inv = frcp(sum);
      for (int o = 0; o < OPS_ + 1; ++o) lg[o] *= inv;
    }
    __syncthreads();
    if (tid < OPS_ + 1) query_attn[((size_t)(r * T_ + t) * B_ + b) * (OPS_ + 1) + tid] = lg[tid];
    __syncthreads();
  }
}

// ------------- entity input projection table: proj[dir][deg(25)][512] -------------
__global__ void eproj_kernel(const float* __restrict__ eemb, const float* __restrict__ eWih,
                             const float* __restrict__ ebih, const float* __restrict__ ebhh,
                             float* __restrict__ proj)
{
  int idx = blockIdx.x * 256 + threadIdx.x;
  if (idx >= 2 * (OPS_ + 1) * G4_) return;
  int j = idx % G4_;
  int v = (idx / G4_) % (OPS_ + 1);
  int dir = idx / (G4_ * (OPS_ + 1));
  const float4* wr = (const float4*)(eWih + (size_t)(dir * G4_ + j) * ED_);
  const float4* er = (const float4*)(eemb + v * ED_);
  float s = ebih[dir * G4_ + j] + ebhh[dir * G4_ + j];
  for (int k = 0; k < ED_ / 4; ++k){
    float4 wv = wr[k], ev = er[k];
    s += wv.x * ev.x + wv.y * ev.y + wv.z * ev.z + wv.w * ev.w;
  }
  proj[idx] = s;
}

// ---- build extended B matrix: wide[dir][j(512)][k(160)] bf16
//      k<128: Whh[j][k];  k=128+v (v<25): proj[dir][v][j];  else 0
__global__ void wbuild_kernel(const float* __restrict__ eWhh, const float* __restrict__ proj,
                              u16* __restrict__ wide)
{
  int idx = blockIdx.x * 256 + threadIdx.x;
  if (idx >= 2 * G4_ * KW_) return;
  int k = idx % KW_;
  int j = (idx / KW_) % G4_;
  int dir = idx / (KW_ * G4_);
  float v = 0.f;
  if (k < H_) v = eWhh[((size_t)dir * G4_ + j) * H_ + k];
  else if (k < H_ + OPS_ + 1) v = proj[(size_t)dir * (OPS_ + 1) * G4_ + (size_t)(k - H_) * G4_ + j];
  wide[idx] = (u16)f2bf(v);
}

// ------ entity BiLSTM (both dirs) + attention softmax, fused: 32 entities/block ------
// K extended to 160: cols 128..152 of the LDS h-rows hold a per-step one-hot of the
// degree, so MFMA computes h@Whh^T + proj[deg] directly into zero-init AGPRs.
__global__ __launch_bounds__(256, 3) void elstm_kernel(
    const int* __restrict__ degs, const u16* __restrict__ wide /* 2,512,160 bf16 */,
    const float* __restrict__ elinW, const float* __restrict__ elinb,
    float* __restrict__ attn /* N,24 */)
{
  int blk = blockIdx.x;
  int tid = threadIdx.x;
  int w = tid >> 6;       // wave 0..3: owns gate cols [w*32, w*32+32) of each gate
  int lane = tid & 63;
  int row = lane >> 4;    // 0..3
  int col = lane & 15;
  int ebase = blk * 32;

  __shared__ __align__(16) short hl[2][32 * HPAD];   // 21 KB
  __shared__ int dlds[32 * MAXDEG_];                 //  1 KB

  for (int i = tid; i < 2 * 32 * HPAD; i += 256) ((short*)hl)[i] = 0;
  if (tid < 32 * MAXDEG_){
    int e = ebase + (tid >> 3);
    if (e >= N_) e = N_ - 1;
    dlds[tid] = degs[e * MAXDEG_ + (tid & 7)];
  }
  __syncthreads();
  if (tid < 32){
    hl[0][tid * HPAD + H_ + dlds[tid * 8 + 0]] = BF16_ONE;            // dir0 first tt=0
    hl[1][tid * HPAD + H_ + dlds[tid * 8 + MAXDEG_ - 1]] = BF16_ONE;  // dir1 first tt=7
  }
  __syncthreads();

  for (int dir = 0; dir < 2; ++dir){
    short* hb = hl[dir];
    const u16* Wd = wide + (size_t)dir * G4_ * KW_;

    float cst[16];
    #pragma unroll
    for (int i = 0; i < 16; ++i) cst[i] = 0.f;

    for (int t = 0; t < MAXDEG_; ++t){
      int tt = dir ? (MAXDEG_ - 1 - t) : t;
      f32x4 acc[16];   // [ct*2 + mt], zero-init -> AGPRs
      #pragma unroll
      for (int i = 0; i < 16; ++i) acc[i] = (f32x4){0.f, 0.f, 0.f, 0.f};

      #pragma unroll
      for (int kc = 0; kc < 5; ++kc){
        int k0 = kc * 32 + row * 8;
        bf16x8 af[2];
        #pragma unroll
        for (int mt = 0; mt < 2; ++mt)
          af[mt] = *(const bf16x8*)&hb[(mt * 16 + col) * HPAD + k0];
        #pragma unroll
        for (int ct = 0; ct < 8; ++ct){
          int gtile = (ct >> 1) * 8 + 2 * w + (ct & 1);
          bf16x8 bfr = *(const bf16x8*)(Wd + (size_t)(gtile * 16 + col) * KW_ + k0);
          #pragma unroll
          for (int mt = 0; mt < 2; ++mt)
            acc[ct * 2 + mt] = __builtin_amdgcn_mfma_f32_16x16x32_bf16(af[mt], bfr, acc[ct * 2 + mt], 0, 0, 0);
        }
      }

      __syncthreads();   // all waves done reading hb

      // --- nonlinearity epilogue: 16 h-units per lane
      #pragma unroll
      for (int mt = 0; mt < 2; ++mt){
        #pragma unroll
        for (int reg = 0; reg < 4; ++reg){
          int m = mt * 16 + row * 4 + reg;
          #pragma unroll
          for (int jj = 0; jj < 2; ++jj){
            int j = w * 32 + jj * 16 + col;
            float gi = acc[(0 + jj) * 2 + mt][reg];
            float gf = acc[(2 + jj) * 2 + mt][reg];
            float gg = acc[(4 + jj) * 2 + mt][reg];
            float go = acc[(6 + jj) * 2 + mt][reg];
            int ci = (mt * 4 + reg) * 2 + jj;
            float cn = fsig(gf) * cst[ci] + fsig(gi) * ftanh(gg);
            float hn = fsig(go) * ftanh(cn);
            cst[ci] = cn;
            hb[m * HPAD + j] = f2bf(hn);
          }
        }
      }
      // --- one-hot maintenance (cols 128..152, disjoint from h writes above)
      if (tid < 32){
        hb[tid * HPAD + H_ + dlds[tid * 8 + tt]] = 0;
        if (t < MAXDEG_ - 1){
          int ttn = dir ? (MAXDEG_ - 2 - t) : (t + 1);
          hb[tid * HPAD + H_ + dlds[tid * 8 + ttn]] = BF16_ONE;
        }
      }
      __syncthreads();   // writes visible before next step's reads
    }
  }

  // ---- attention epilogue: logits + softmax over 24 ops, 8 lanes per entity ----
  int nl = tid >> 3;     // local entity 0..31
  int sub = tid & 7;     // owns ops [sub*3, sub*3+3)
  float lgv[3];
  #pragma unroll
  for (int i = 0; i < 3; ++i) lgv[i] = elinb[sub * 3 + i];
  for (int k = 0; k < 2 * H_; ++k){
    float hv = bf2f((u16)hl[k >> 7][nl * HPAD + (k & 127)]);
    #pragma unroll
    for (int i = 0; i < 3; ++i)
      lgv[i] += hv * elinW[(sub * 3 + i) * 2 * H_ + k];   // 24 KB, L1-resident
  }
  float m = lgv[0];
  #pragma unroll
  for (int i = 1; i < 3; ++i) m = fmaxf(m, lgv[i]);
  m = fmaxf(m, __shfl_xor(m, 1));
  m = fmaxf(m, __shfl_xor(m, 2));
  m = fmaxf(m, __shfl_xor(m, 4));
  float s = 0.f;
  #pragma unroll
  for (int i = 0; i < 3; ++i) s += __expf(lgv[i] - m);
  s += __shfl_xor(s, 1);
  s += __shfl_xor(s, 2);
  s += __shfl_xor(s, 4);
  int n = ebase + nl;
  if (n < N_){
    float inv = frcp(s);
    #pragma unroll
    for (int i = 0; i < 3; ++i)
      attn[(size_t)n * OPS_ + sub * 3 + i] = __expf(lgv[i] - m) * inv;
  }
}

__global__ void wgather_kernel(const float* __restrict__ attn, const int* __restrict__ rels,
                               const int* __restrict__ theads, float* __restrict__ wbuf)
{
  int e = blockIdx.x * 256 + threadIdx.x;
  if (e < E_) wbuf[e] = attn[(size_t)theads[e] * OPS_ + rels[e]];
}

// ------------- propagation: memory layout (N,B) -------------
__global__ void initprop_kernel(const int* __restrict__ heads, const float* __restrict__ qa,
                                float* __restrict__ cur, float* __restrict__ nxt)
{
  int idx = blockIdx.x * 256 + threadIdx.x;
  if (idx < N_ * B_){
    int b = idx & (B_ - 1);
    int n = idx >> 5;
    float v = (heads[b] == n) ? 1.0f : 0.0f;
    cur[idx] = v;
    nxt[idx] = v * qa[b * (OPS_ + 1) + OPS_];
  }
}

__global__ void scatter_kernel(const float* __restrict__ min_, float* __restrict__ mout,
                               const float* __restrict__ qa,
                               const int* __restrict__ rels, const int* __restrict__ theads,
                               const int* __restrict__ ttails, const float* __restrict__ wbuf)
{
  __shared__ float qas[B_ * (OPS_ + 1)];
  int tid = threadIdx.x;
  for (int i = tid; i < B_ * (OPS_ + 1); i += 256) qas[i] = qa[i];
  __syncthreads();
  int g = blockIdx.x * 256 + tid;     // g = e*32 + b
  if (g < E_ * B_){
    int b = g & (B_ - 1);
    int e = g >> 5;
    int rel = rels[e];
    float we = wbuf[e];
    int hh = theads[e], tt = ttails[e];
    float mh = min_[(size_t)hh * B_ + b];
    float mt = min_[(size_t)tt * B_ + b];
    float fwd = qas[b * (OPS_ + 1) + rel] * we * mh;
    float rev = qas[b * (OPS_ + 1) + rel + OPS_ / 2] * we * mt;
    if (fwd != 0.f) atomicAdd(&mout[(size_t)tt * B_ + b], fwd);
    if (rev != 0.f) atomicAdd(&mout[(size_t)hh * B_ + b], rev);
  }
}

__global__ void rowsum_kernel(const float* __restrict__ m, float* __restrict__ sums)
{
  __shared__ float red[256];
  int tid = threadIdx.x;
  float s = 0.f;
  for (int idx = blockIdx.x * 256 + tid; idx < N_ * B_; idx += gridDim.x * 256)
    s += m[idx];
  red[tid] = s;
  __syncthreads();
  if (tid < B_){
    float t = 0.f;
    for (int i = tid; i < 256; i += B_) t += red[i];
    atomicAdd(&sums[tid], t);
  }
}

// normalize a; mode 0: also prep next selfadd (nextbuf = v*qa_next[b][24]);
// mode 1: also accumulate into logacc
__global__ void normfuse_kernel(float* __restrict__ a, const float* __restrict__ sums,
                                float* __restrict__ nextbuf, const float* __restrict__ qa_next,
                                float* __restrict__ logacc, int mode)
{
  int idx = blockIdx.x * 256 + threadIdx.x;
  if (idx < N_ * B_){
    int b = idx & (B_ - 1);
    float v = a[idx] * frcp(fmaxf(1e-20f, sums[b]));
    a[idx] = v;
    if (mode == 0) nextbuf[idx] = v * qa_next[b * (OPS_ + 1) + OPS_];
    else logacc[idx] += v;
  }
}

// ------------- final transpose: acc (N,B) -> out (B,N), LDS-tiled -------------
__global__ void transpose_kernel(const float* __restrict__ acc, float* __restrict__ out)
{
  __shared__ float t[B_][72];  // [b][nl], nl<64
  int n0 = blockIdx.x * 64;
  int tid = threadIdx.x;
  for (int i = tid; i < 64 * B_; i += 256){
    int nl = i >> 5, b = i & 31;
    int n = n0 + nl;
    t[b][nl] = (n < N_) ? acc[(size_t)n * B_ + b] : 0.f;
  }
  __syncthreads();
  for (int i = tid; i < 64 * B_; i += 256){
    int b = i >> 6, nl = i & 63;
    int n = n0 + nl;
    if (n < N_) out[(size_t)b * N_ + n] = t[b][nl];
  }
}

extern "C" void kernel_launch(void* const* d_in, const int* in_sizes, int n_in,
                              void* d_out, int out_size, void* d_ws, size_t ws_size,
                              hipStream_t stream)
{
  const int*   queries = (const int*)d_in[0];
  const int*   heads   = (const int*)d_in[1];
  const int*   rels    = (const int*)d_in[2];
  const int*   t_heads = (const int*)d_in[3];
  const int*   t_tails = (const int*)d_in[4];
  const int*   edeg    = (const int*)d_in[5];
  const float* qemb    = (const float*)d_in[6];
  const float* eemb    = (const float*)d_in[7];
  const float* qWih    = (const float*)d_in[8];
  const float* qWhh    = (const float*)d_in[9];
  const float* qbih    = (const float*)d_in[10];
  const float* qbhh    = (const float*)d_in[11];
  const float* eWih    = (const float*)d_in[12];
  const float* eWhh    = (const float*)d_in[13];
  const float* ebih    = (const float*)d_in[14];
  const float* ebhh    = (const float*)d_in[15];
  const float* qlinW   = (const float*)d_in[16];
  const float* qlinb   = (const float*)d_in[17];
  const float* elinW   = (const float*)d_in[18];
  const float* elinb   = (const float*)d_in[19];
  float* out = (float*)d_out;

  char* ws = (char*)d_ws;
  size_t off = 0;
  auto alloc = [&](size_t bytes){ void* p = ws + off; off += (bytes + 255) & ~(size_t)255; return p; };
  float* query_attn = (float*)alloc((size_t)R_ * T_ * B_ * (OPS_ + 1) * 4);  //  29 KB
  float* proj       = (float*)alloc((size_t)2 * (OPS_ + 1) * G4_ * 4);       // 102 KB
  u16*   wide       = (u16*)  alloc((size_t)2 * G4_ * KW_ * 2);              // 320 KB
  float* attn       = (float*)alloc((size_t)N_ * OPS_ * 4);                  // 4.8 MB
  float* wbuf       = (float*)alloc((size_t)E_ * 4);                         // 1.6 MB
  float* mem0       = (float*)alloc((size_t)N_ * B_ * 4);                    // 6.4 MB
  float* mem1       = (float*)alloc((size_t)N_ * B_ * 4);                    // 6.4 MB
  float* logacc     = (float*)alloc((size_t)N_ * B_ * 4);                    // 6.4 MB
  float* sums9      = (float*)alloc((size_t)R_ * T_ * B_ * 4);               // 1.1 KB
  // total ~26 MB

  hipMemsetAsync(logacc, 0, (size_t)N_ * B_ * 4, stream);
  hipMemsetAsync(sums9, 0, (size_t)R_ * T_ * B_ * 4, stream);

  qattn_kernel<<<R_ * B_, 256, 0, stream>>>(queries, qemb, qWih, qWhh, qbih, qbhh,
                                            qlinW, qlinb, query_attn);
  eproj_kernel<<<(2 * (OPS_ + 1) * G4_ + 255) / 256, 256, 0, stream>>>(eemb, eWih, ebih, ebhh, proj);
  wbuild_kernel<<<(2 * G4_ * KW_ + 255) / 256, 256, 0, stream>>>(eWhh, proj, wide);
  elstm_kernel<<<(N_ + 31) / 32, 256, 0, stream>>>(edeg, wide, elinW, elinb, attn);
  wgather_kernel<<<(E_ + 255) / 256, 256, 0, stream>>>(attn, rels, t_heads, wbuf);

  const int NB_BLK = (N_ * B_ + 255) / 256;
  for (int r = 0; r < R_; ++r){
    const float* qa0 = query_attn + (size_t)(r * T_ + 0) * B_ * (OPS_ + 1);
    initprop_kernel<<<NB_BLK, 256, 0, stream>>>(heads, qa0, mem0, mem1);
    float* cur = mem0;
    float* nxt = mem1;
    for (int t = 0; t < T_; ++t){
      const float* qa = query_attn + (size_t)(r * T_ + t) * B_ * (OPS_ + 1);
      const float* qn = query_attn + (size_t)(r * T_ + t + 1) * B_ * (OPS_ + 1); // used only if t<T_-1
      float* slot = sums9 + (size_t)(r * T_ + t) * B_;
      scatter_kernel<<<(E_ * B_ + 255) / 256, 256, 0, stream>>>(cur, nxt, qa, rels, t_heads, t_tails, wbuf);
      rowsum_kernel<<<512, 256, 0, stream>>>(nxt, slot);
      if (t < T_ - 1)
        normfuse_kernel<<<NB_BLK, 256, 0, stream>>>(nxt, slot, cur, qn, logacc, 0);
      else
        normfuse_kernel<<<NB_BLK, 256, 0, stream>>>(nxt, slot, cur, qa, logacc, 1);
      float* tmp = cur; cur = nxt; nxt = tmp;
    }
  }
  transpose_kernel<<<(N_ + 63) / 64, 256, 0, stream>>>(logacc, out);
}

// Round 6
// 1078.809 us; speedup vs baseline: 1.4824x; 1.4824x over previous
//
#include <hip/hip_runtime.h>

#define R_ 3
#define T_ 3
#define N_ 50000
#define OPS_ 24
#define E_ 400000
#define B_ 32
#define MAXDEG_ 8
#define QD_ 128
#define ED_ 128
#define H_ 128
#define G4_ (4*H_)   /* 512 */
#define KW_ 160      /* extended K: 128 h + 25 one-hot + 7 pad */
#define HPAD 168     /* padded LDS row (bf16 elems), 16B-aligned (336 B) */
#define PSLOTS 64    /* partial row-sum slots per (r,t) */

typedef unsigned short u16;
typedef __attribute__((ext_vector_type(8))) short bf16x8;   // 8 bf16 = 4 VGPRs
typedef __attribute__((ext_vector_type(4))) float f32x4;

#define BF16_ONE ((short)0x3F80)

__device__ __forceinline__ short f2bf(float f){
  union { float f; unsigned u; } v; v.f = f;
  unsigned r = v.u + 0x7fffu + ((v.u >> 16) & 1u);
  return (short)(r >> 16);
}
__device__ __forceinline__ float bf2f(u16 u){
  union { unsigned u; float f; } v; v.u = ((unsigned)u) << 16; return v.f;
}
__device__ __forceinline__ float frcp(float x){ return __builtin_amdgcn_rcpf(x); }
__device__ __forceinline__ float fsig(float x){ return frcp(1.0f + __expf(-x)); }
// tanh(x) = 2*sigmoid(2x) - 1
__device__ __forceinline__ float ftanh(float x){
  return __builtin_fmaf(2.0f, fsig(2.0f * x), -1.0f);
}

// ---------------- query BiLSTM + attention: one block per (r,b) ----------------
__global__ void qattn_kernel(const int* __restrict__ queries, const float* __restrict__ qemb,
    const float* __restrict__ qWih, const float* __restrict__ qWhh,
    const float* __restrict__ qbih, const float* __restrict__ qbhh,
    const float* __restrict__ qlinW, const float* __restrict__ qlinb,
    float* __restrict__ query_attn /* R,T,B,25 */)
{
  int r = blockIdx.x / B_;
  int b = blockIdx.x % B_;
  int tid = threadIdx.x;   // 256
  __shared__ float x[QD_];
  __shared__ float gx[G4_];
  __shared__ float h[H_], c[H_];
  __shared__ float gtmp[G4_];
  __shared__ float hh[2][T_][H_];
  __shared__ float lg[OPS_ + 1];

  int q = queries[b];
  if (tid < QD_) x[tid] = qemb[q * QD_ + tid];
  __syncthreads();

  for (int dir = 0; dir < 2; ++dir){
    const float* Wih = qWih + (size_t)(r * 2 + dir) * G4_ * QD_;
    const float* Whh = qWhh + (size_t)(r * 2 + dir) * G4_ * H_;
    const float* bih = qbih + (r * 2 + dir) * G4_;
    const float* bhh = qbhh + (r * 2 + dir) * G4_;
    for (int j = tid; j < G4_; j += 256){
      const float4* wr = (const float4*)(Wih + (size_t)j * QD_);
      float s = bih[j] + bhh[j];
      for (int k = 0; k < QD_ / 4; ++k){
        float4 wv = wr[k];
        s += wv.x * x[4*k] + wv.y * x[4*k+1] + wv.z * x[4*k+2] + wv.w * x[4*k+3];
      }
      gx[j] = s;
    }
    if (tid < H_){ h[tid] = 0.f; c[tid] = 0.f; }
    __syncthreads();
    for (int t = 0; t < T_; ++t){
      for (int j = tid; j < G4_; j += 256){
        const float4* wr = (const float4*)(Whh + (size_t)j * H_);
        float s = 0.f;
        for (int k = 0; k < H_ / 4; ++k){
          float4 wv = wr[k];
          s += wv.x * h[4*k] + wv.y * h[4*k+1] + wv.z * h[4*k+2] + wv.w * h[4*k+3];
        }
        gtmp[j] = gx[j] + s;
      }
      __syncthreads();
      if (tid < H_){
        float gi = gtmp[tid], gf = gtmp[tid + H_], gg = gtmp[tid + 2*H_], go = gtmp[tid + 3*H_];
        float cn = fsig(gf) * c[tid] + fsig(gi) * ftanh(gg);
        float hn = fsig(go) * ftanh(cn);
        c[tid] = cn; h[tid] = hn;
        hh[dir][t][tid] = hn;
      }
      __syncthreads();
    }
  }

  for (int t = 0; t < T_; ++t){
    if (tid < OPS_ + 1){
      const float* wr = qlinW + tid * (2 * H_);
      float s = qlinb[tid];
      for (int k = 0; k < H_; ++k) s += wr[k] * hh[0][t][k];
      for (int k = 0; k < H_; ++k) s += wr[H_ + k] * hh[1][T_ - 1 - t][k];
      lg[tid] = s;
    }
    __syncthreads();
    if (tid == 0){
      float m = -1e30f;
      for (int o = 0; o < OPS_ + 1; ++o) m = fmaxf(m, lg[o]);
      float sum = 0.f;
      for (int o = 0; o < OPS_ + 1; ++o){ float e = __expf(lg[o] - m); lg[o] = e; sum += e; }
      float inv = frcp(sum);
      for (int o = 0; o < OPS_ + 1; ++o) lg[o] *= inv;
    }
    __syncthreads();
    if (tid < OPS_ + 1) query_attn[((size_t)(r * T_ + t) * B_ + b) * (OPS_ + 1) + tid] = lg[tid];
    __syncthreads();
  }
}

// ------------- entity input projection table: proj[dir][deg(25)][512] -------------
__global__ void eproj_kernel(const float* __restrict__ eemb, const float* __restrict__ eWih,
                             const float* __restrict__ ebih, const float* __restrict__ ebhh,
                             float* __restrict__ proj)
{
  int idx = blockIdx.x * 256 + threadIdx.x;
  if (idx >= 2 * (OPS_ + 1) * G4_) return;
  int j = idx % G4_;
  int v = (idx / G4_) % (OPS_ + 1);
  int dir = idx / (G4_ * (OPS_ + 1));
  const float4* wr = (const float4*)(eWih + (size_t)(dir * G4_ + j) * ED_);
  const float4* er = (const float4*)(eemb + v * ED_);
  float s = ebih[dir * G4_ + j] + ebhh[dir * G4_ + j];
  for (int k = 0; k < ED_ / 4; ++k){
    float4 wv = wr[k], ev = er[k];
    s += wv.x * ev.x + wv.y * ev.y + wv.z * ev.z + wv.w * ev.w;
  }
  proj[idx] = s;
}

// ---- build extended B matrix: wide[dir][j(512)][k(160)] bf16
//      k<128: Whh[j][k];  k=128+v (v<25): proj[dir][v][j];  else 0
__global__ void wbuild_kernel(const float* __restrict__ eWhh, const float* __restrict__ proj,
                              u16* __restrict__ wide)
{
  int idx = blockIdx.x * 256 + threadIdx.x;
  if (idx >= 2 * G4_ * KW_) return;
  int k = idx % KW_;
  int j = (idx / KW_) % G4_;
  int dir = idx / (KW_ * G4_);
  float v = 0.f;
  if (k < H_) v = eWhh[((size_t)dir * G4_ + j) * H_ + k];
  else if (k < H_ + OPS_ + 1) v = proj[(size_t)dir * (OPS_ + 1) * G4_ + (size_t)(k - H_) * G4_ + j];
  wide[idx] = (u16)f2bf(v);
}

// ------ entity BiLSTM (both dirs) + attention softmax, fused: 32 entities/block ------
// K extended to 160: cols 128..152 of the LDS h-rows hold a per-step one-hot of the
// degree, so MFMA computes h@Whh^T + proj[deg] directly into zero-init AGPRs.
// NOTE: min-waves bound of 3 (rounds 4/5) forced VGPR=84 and ~1.7 GB of scratch
// spill traffic that also thrashed L2; (256,2) keeps the ~170-reg working set
// spill-free (round-3 evidence: unbounded -> VGPR 232, FETCH 2.4 MB).
__global__ __launch_bounds__(256, 2) void elstm_kernel(
    const int* __restrict__ degs, const u16* __restrict__ wide /* 2,512,160 bf16 */,
    const float* __restrict__ elinW, const float* __restrict__ elinb,
    float* __restrict__ attn /* N,24 */)
{
  int blk = blockIdx.x;
  int tid = threadIdx.x;
  int w = tid >> 6;       // wave 0..3: owns gate cols [w*32, w*32+32) of each gate
  int lane = tid & 63;
  int row = lane >> 4;    // 0..3
  int col = lane & 15;
  int ebase = blk * 32;

  __shared__ __align__(16) short hl[2][32 * HPAD];   // 21 KB
  __shared__ int dlds[32 * MAXDEG_];                 //  1 KB

  for (int i = tid; i < 2 * 32 * HPAD; i += 256) ((short*)hl)[i] = 0;
  if (tid < 32 * MAXDEG_){
    int e = ebase + (tid >> 3);
    if (e >= N_) e = N_ - 1;
    dlds[tid] = degs[e * MAXDEG_ + (tid & 7)];
  }
  __syncthreads();
  if (tid < 32){
    hl[0][tid * HPAD + H_ + dlds[tid * 8 + 0]] = BF16_ONE;            // dir0 first tt=0
    hl[1][tid * HPAD + H_ + dlds[tid * 8 + MAXDEG_ - 1]] = BF16_ONE;  // dir1 first tt=7
  }
  __syncthreads();

  for (int dir = 0; dir < 2; ++dir){
    short* hb = hl[dir];
    const u16* Wd = wide + (size_t)dir * G4_ * KW_;

    float cst[16];
    #pragma unroll
    for (int i = 0; i < 16; ++i) cst[i] = 0.f;

    for (int t = 0; t < MAXDEG_; ++t){
      int tt = dir ? (MAXDEG_ - 1 - t) : t;
      f32x4 acc[16];   // [ct*2 + mt], zero-init -> AGPRs
      #pragma unroll
      for (int i = 0; i < 16; ++i) acc[i] = (f32x4){0.f, 0.f, 0.f, 0.f};

      #pragma unroll
      for (int kc = 0; kc < 5; ++kc){
        int k0 = kc * 32 + row * 8;
        bf16x8 af[2];
        #pragma unroll
        for (int mt = 0; mt < 2; ++mt)
          af[mt] = *(const bf16x8*)&hb[(mt * 16 + col) * HPAD + k0];
        #pragma unroll
        for (int ct = 0; ct < 8; ++ct){
          int gtile = (ct >> 1) * 8 + 2 * w + (ct & 1);
          bf16x8 bfr = *(const bf16x8*)(Wd + (size_t)(gtile * 16 + col) * KW_ + k0);
          #pragma unroll
          for (int mt = 0; mt < 2; ++mt)
            acc[ct * 2 + mt] = __builtin_amdgcn_mfma_f32_16x16x32_bf16(af[mt], bfr, acc[ct * 2 + mt], 0, 0, 0);
        }
      }

      __syncthreads();   // all waves done reading hb

      // --- nonlinearity epilogue: 16 h-units per lane
      #pragma unroll
      for (int mt = 0; mt < 2; ++mt){
        #pragma unroll
        for (int reg = 0; reg < 4; ++reg){
          int m = mt * 16 + row * 4 + reg;
          #pragma unroll
          for (int jj = 0; jj < 2; ++jj){
            int j = w * 32 + jj * 16 + col;
            float gi = acc[(0 + jj) * 2 + mt][reg];
            float gf = acc[(2 + jj) * 2 + mt][reg];
            float gg = acc[(4 + jj) * 2 + mt][reg];
            float go = acc[(6 + jj) * 2 + mt][reg];
            int ci = (mt * 4 + reg) * 2 + jj;
            float cn = fsig(gf) * cst[ci] + fsig(gi) * ftanh(gg);
            float hn = fsig(go) * ftanh(cn);
            cst[ci] = cn;
            hb[m * HPAD + j] = f2bf(hn);
          }
        }
      }
      // --- one-hot maintenance (cols 128..152, disjoint from h writes above)
      if (tid < 32){
        hb[tid * HPAD + H_ + dlds[tid * 8 + tt]] = 0;
        if (t < MAXDEG_ - 1){
          int ttn = dir ? (MAXDEG_ - 2 - t) : (t + 1);
          hb[tid * HPAD + H_ + dlds[tid * 8 + ttn]] = BF16_ONE;
        }
      }
      __syncthreads();   // writes visible before next step's reads
    }
  }

  // ---- attention epilogue: logits + softmax over 24 ops, 8 lanes per entity ----
  int nl = tid >> 3;     // local entity 0..31
  int sub = tid & 7;     // owns ops [sub*3, sub*3+3)
  float lgv[3];
  #pragma unroll
  for (int i = 0; i < 3; ++i) lgv[i] = elinb[sub * 3 + i];
  for (int k = 0; k < 2 * H_; ++k){
    float hv = bf2f((u16)hl[k >> 7][nl * HPAD + (k & 127)]);
    #pragma unroll
    for (int i = 0; i < 3; ++i)
      lgv[i] += hv * elinW[(sub * 3 + i) * 2 * H_ + k];   // 24 KB, L1/L2-resident
  }
  float m = lgv[0];
  #pragma unroll
  for (int i = 1; i < 3; ++i) m = fmaxf(m, lgv[i]);
  m = fmaxf(m, __shfl_xor(m, 1));
  m = fmaxf(m, __shfl_xor(m, 2));
  m = fmaxf(m, __shfl_xor(m, 4));
  float s = 0.f;
  #pragma unroll
  for (int i = 0; i < 3; ++i) s += __expf(lgv[i] - m);
  s += __shfl_xor(s, 1);
  s += __shfl_xor(s, 2);
  s += __shfl_xor(s, 4);
  int n = ebase + nl;
  if (n < N_){
    float inv = frcp(s);
    #pragma unroll
    for (int i = 0; i < 3; ++i)
      attn[(size_t)n * OPS_ + sub * 3 + i] = __expf(lgv[i] - m) * inv;
  }
}

__global__ void wgather_kernel(const float* __restrict__ attn, const int* __restrict__ rels,
                               const int* __restrict__ theads, float* __restrict__ wbuf)
{
  int e = blockIdx.x * 256 + threadIdx.x;
  if (e < E_) wbuf[e] = attn[(size_t)theads[e] * OPS_ + rels[e]];
}

// ------------- propagation: memory layout (N,B) -------------
__global__ void initprop_kernel(const int* __restrict__ heads, const float* __restrict__ qa,
                                float* __restrict__ cur, float* __restrict__ nxt)
{
  int idx = blockIdx.x * 256 + threadIdx.x;
  if (idx < N_ * B_){
    int b = idx & (B_ - 1);
    int n = idx >> 5;
    float v = (heads[b] == n) ? 1.0f : 0.0f;
    cur[idx] = v;
    nxt[idx] = v * qa[b * (OPS_ + 1) + OPS_];
  }
}

// grid-stride edge scatter + fused row-sum partials.
// Each tile = 8 edges x 32 batch lanes. Per-block LDS reduce of fwd+rev,
// then 32 atomics into this (r,t)'s partial slot array [PSLOTS][B].
__global__ __launch_bounds__(256) void scatter_kernel(
    const float* __restrict__ min_, float* __restrict__ mout,
    const float* __restrict__ qa,
    const int* __restrict__ rels, const int* __restrict__ theads,
    const int* __restrict__ ttails, const float* __restrict__ wbuf,
    float* __restrict__ partial /* PSLOTS x B */)
{
  __shared__ float qas[B_ * (OPS_ + 1)];
  __shared__ float red[B_];
  int tid = threadIdx.x;
  for (int i = tid; i < B_ * (OPS_ + 1); i += 256) qas[i] = qa[i];
  if (tid < B_) red[tid] = 0.f;
  __syncthreads();
  int b = tid & (B_ - 1);
  int eo = tid >> 5;        // 0..7
  float local = 0.f;
  const int TILES = E_ * B_ / 256;   // 50000
  for (int tile = blockIdx.x; tile < TILES; tile += gridDim.x){
    int e = tile * 8 + eo;
    int rel = rels[e];
    float we = wbuf[e];
    int hh = theads[e], tt = ttails[e];
    float mh = min_[(size_t)hh * B_ + b];
    float mt = min_[(size_t)tt * B_ + b];
    float fwd = qas[b * (OPS_ + 1) + rel] * we * mh;
    float rev = qas[b * (OPS_ + 1) + rel + OPS_ / 2] * we * mt;
    local += fwd + rev;
    if (fwd != 0.f) atomicAdd(&mout[(size_t)tt * B_ + b], fwd);
    if (rev != 0.f) atomicAdd(&mout[(size_t)hh * B_ + b], rev);
  }
  atomicAdd(&red[b], local);
  __syncthreads();
  if (tid < B_) atomicAdd(&partial[(blockIdx.x & (PSLOTS - 1)) * B_ + tid], red[tid]);
}

// normalize a using sums reduced from partials (+ self term qa_cur[b][24], since
// the pre-scatter nxt = memory*qa24 sums to qa24 per batch: memory is normalized);
// mode 0: also prep next selfadd (nextbuf = v*qa_next[b][24]); mode 1: logacc += v
__global__ void normfuse_kernel(float* __restrict__ a, const float* __restrict__ partial,
                                const float* __restrict__ qa_cur,
                                float* __restrict__ nextbuf, const float* __restrict__ qa_next,
                                float* __restrict__ logacc, int mode)
{
  __shared__ float smem[8][B_];
  __shared__ float sinv[B_];
  int tid = threadIdx.x;
  {
    int b = tid & (B_ - 1), pr = tid >> 5;   // pr 0..7
    float s = 0.f;
    #pragma unroll
    for (int k = 0; k < 8; ++k) s += partial[(pr + 8 * k) * B_ + b];
    smem[pr][b] = s;
  }
  __syncthreads();
  if (tid < B_){
    float s = qa_cur[tid * (OPS_ + 1) + OPS_];
    #pragma unroll
    for (int k = 0; k < 8; ++k) s += smem[k][tid];
    sinv[tid] = frcp(fmaxf(1e-20f, s));
  }
  __syncthreads();
  int idx = blockIdx.x * 256 + tid;
  if (idx < N_ * B_){
    int b = idx & (B_ - 1);
    float v = a[idx] * sinv[b];
    a[idx] = v;
    if (mode == 0) nextbuf[idx] = v * qa_next[b * (OPS_ + 1) + OPS_];
    else logacc[idx] += v;
  }
}

// ------------- final transpose: acc (N,B) -> out (B,N), LDS-tiled -------------
__global__ void transpose_kernel(const float* __restrict__ acc, float* __restrict__ out)
{
  __shared__ float t[B_][72];  // [b][nl], nl<64
  int n0 = blockIdx.x * 64;
  int tid = threadIdx.x;
  for (int i = tid; i < 64 * B_; i += 256){
    int nl = i >> 5, b = i & 31;
    int n = n0 + nl;
    t[b][nl] = (n < N_) ? acc[(size_t)n * B_ + b] : 0.f;
  }
  __syncthreads();
  for (int i = tid; i < 64 * B_; i += 256){
    int b = i >> 6, nl = i & 63;
    int n = n0 + nl;
    if (n < N_) out[(size_t)b * N_ + n] = t[b][nl];
  }
}

extern "C" void kernel_launch(void* const* d_in, const int* in_sizes, int n_in,
                              void* d_out, int out_size, void* d_ws, size_t ws_size,
                              hipStream_t stream)
{
  const int*   queries = (const int*)d_in[0];
  const int*   heads   = (const int*)d_in[1];
  const int*   rels    = (const int*)d_in[2];
  const int*   t_heads = (const int*)d_in[3];
  const int*   t_tails = (const int*)d_in[4];
  const int*   edeg    = (const int*)d_in[5];
  const float* qemb    = (const float*)d_in[6];
  const float* eemb    = (const float*)d_in[7];
  const float* qWih    = (const float*)d_in[8];
  const float* qWhh    = (const float*)d_in[9];
  const float* qbih    = (const float*)d_in[10];
  const float* qbhh    = (const float*)d_in[11];
  const float* eWih    = (const float*)d_in[12];
  const float* eWhh    = (const float*)d_in[13];
  const float* ebih    = (const float*)d_in[14];
  const float* ebhh    = (const float*)d_in[15];
  const float* qlinW   = (const float*)d_in[16];
  const float* qlinb   = (const float*)d_in[17];
  const float* elinW   = (const float*)d_in[18];
  const float* elinb   = (const float*)d_in[19];
  float* out = (float*)d_out;

  char* ws = (char*)d_ws;
  size_t off = 0;
  auto alloc = [&](size_t bytes){ void* p = ws + off; off += (bytes + 255) & ~(size_t)255; return p; };
  float* query_attn = (float*)alloc((size_t)R_ * T_ * B_ * (OPS_ + 1) * 4);  //  29 KB
  float* proj       = (float*)alloc((size_t)2 * (OPS_ + 1) * G4_ * 4);       // 102 KB
  u16*   wide       = (u16*)  alloc((size_t)2 * G4_ * KW_ * 2);              // 320 KB
  float* attn       = (float*)alloc((size_t)N_ * OPS_ * 4);                  // 4.8 MB
  float* wbuf       = (float*)alloc((size_t)E_ * 4);                         // 1.6 MB
  float* mem0       = (float*)alloc((size_t)N_ * B_ * 4);                    // 6.4 MB
  float* mem1       = (float*)alloc((size_t)N_ * B_ * 4);                    // 6.4 MB
  float* logacc     = (float*)alloc((size_t)N_ * B_ * 4);                    // 6.4 MB
  float* sumsP      = (float*)alloc((size_t)R_ * T_ * PSLOTS * B_ * 4);      // 73 KB
  // total ~26 MB

  hipMemsetAsync(logacc, 0, (size_t)N_ * B_ * 4, stream);
  hipMemsetAsync(sumsP, 0, (size_t)R_ * T_ * PSLOTS * B_ * 4, stream);

  qattn_kernel<<<R_ * B_, 256, 0, stream>>>(queries, qemb, qWih, qWhh, qbih, qbhh,
                                            qlinW, qlinb, query_attn);
  eproj_kernel<<<(2 * (OPS_ + 1) * G4_ + 255) / 256, 256, 0, stream>>>(eemb, eWih, ebih, ebhh, proj);
  wbuild_kernel<<<(2 * G4_ * KW_ + 255) / 256, 256, 0, stream>>>(eWhh, proj, wide);
  elstm_kernel<<<(N_ + 31) / 32, 256, 0, stream>>>(edeg, wide, elinW, elinb, attn);
  wgather_kernel<<<(E_ + 255) / 256, 256, 0, stream>>>(attn, rels, t_heads, wbuf);

  const int NB_BLK = (N_ * B_ + 255) / 256;
  const int SC_BLK = 6250;   // 8 tiles per block
  for (int r = 0; r < R_; ++r){
    const float* qa0 = query_attn + (size_t)(r * T_ + 0) * B_ * (OPS_ + 1);
    initprop_kernel<<<NB_BLK, 256, 0, stream>>>(heads, qa0, mem0, mem1);
    float* cur = mem0;
    float* nxt = mem1;
    for (int t = 0; t < T_; ++t){
      const float* qa = query_attn + (size_t)(r * T_ + t) * B_ * (OPS_ + 1);
      const float* qn = query_attn + (size_t)(r * T_ + t + 1) * B_ * (OPS_ + 1); // used only if t<T_-1
      float* pslot = sumsP + (size_t)(r * T_ + t) * PSLOTS * B_;
      scatter_kernel<<<SC_BLK, 256, 0, stream>>>(cur, nxt, qa, rels, t_heads, t_tails, wbuf, pslot);
      if (t < T_ - 1)
        normfuse_kernel<<<NB_BLK, 256, 0, stream>>>(nxt, pslot, qa, cur, qn, logacc, 0);
      else
        normfuse_kernel<<<NB_BLK, 256, 0, stream>>>(nxt, pslot, qa, cur, qa, logacc, 1);
      float* tmp = cur; cur = nxt; nxt = tmp;
    }
  }
  transpose_kernel<<<(N_ + 63) / 64, 256, 0, stream>>>(logacc, out);
}